// Round 13
// baseline (206.379 us; speedup 1.0000x reference)
//
#include <hip/hip_runtime.h>

typedef __attribute__((ext_vector_type(8))) short short8;
typedef __attribute__((ext_vector_type(4))) float f32x4;
typedef __attribute__((ext_vector_type(4))) float f4;
typedef __attribute__((ext_vector_type(4))) unsigned short u16x4;

#define MFMA_B16 __builtin_amdgcn_mfma_f32_16x16x32_bf16

__device__ __forceinline__ unsigned short f2bf(float f) {
    union { float f; unsigned int u; } v; v.f = f;
    unsigned int r = v.u + 0x7fffu + ((v.u >> 16) & 1u);
    return (unsigned short)(r >> 16);
}
__device__ __forceinline__ float bf2f(unsigned short h) {
    union { unsigned int u; float f; } v; v.u = ((unsigned int)h) << 16;
    return v.f;
}
__device__ __forceinline__ float fexp2(float x) {
    float r; asm("v_exp_f32 %0, %1" : "=v"(r) : "v"(x)); return r;
}
__device__ __forceinline__ unsigned int cvt_pk_bf16(float lo, float hi) {
    unsigned int r;
    asm("v_cvt_pk_bf16_f32 %0, %1, %2" : "=v"(r) : "v"(lo), "v"(hi));
    return r;
}
__device__ __forceinline__ void gload_lds16(const void* g, void* l) {
    __builtin_amdgcn_global_load_lds(
        (const __attribute__((address_space(1))) unsigned int*)g,
        (__attribute__((address_space(3))) unsigned int*)l, 16, 0, 0);
}

// ---------------- merged conversions (one launch) ----------------
__global__ void conv_all(const float* __restrict__ x, unsigned short* __restrict__ xb,
                         const float* __restrict__ wq, const float* __restrict__ wkv,
                         unsigned short* __restrict__ wt_qkv,
                         const float* __restrict__ wo, unsigned short* __restrict__ wt_o) {
    __shared__ float tile[64 * 65];
    const int bx = blockIdx.x, tid = threadIdx.x;
    if (bx < 8192) {
        int i = bx * 256 + tid;
        f4 v = ((const f4*)x)[i];
        u16x4 o;
        o[0] = f2bf(v[0]); o[1] = f2bf(v[1]); o[2] = f2bf(v[2]); o[3] = f2bf(v[3]);
        ((u16x4*)xb)[i] = o;
        return;
    }
    if (bx < 10240) {
        const int flat = bx - 8192;
        const int d0 = (flat & 31) * 64, f0 = (flat >> 5) * 64;
        const int head = f0 >> 7;
        const int h0 = f0 & 127;
        const float* src;
        float scl;
        if (head < 16)      { src = wq + (size_t)head * 2048 * 128;         scl = 0.08838834764831845f; }
        else if (head < 24) { src = wkv + (size_t)(head - 16) * 2048 * 128; scl = 0.057707801635558534f; }
        else                { src = wkv + (size_t)(head - 16) * 2048 * 128; scl = 1.f; }
        {
            int hh = tid & 63, dq = tid >> 6;
            #pragma unroll
            for (int r = 0; r < 16; ++r) {
                int dd = r * 4 + dq;
                tile[dd * 65 + hh] = src[(size_t)(d0 + dd) * 128 + h0 + hh] * scl;
            }
        }
        __syncthreads();
        {
            int dd = tid & 63, fq = tid >> 6;
            #pragma unroll
            for (int r = 0; r < 16; ++r) {
                int fl = r * 4 + fq;
                wt_qkv[(size_t)(f0 + fl) * 2048 + d0 + dd] = f2bf(tile[dd * 65 + fl]);
            }
        }
        return;
    }
    {
        const int flat = bx - 10240;
        const int d0 = (flat & 31) * 64, r0 = (flat >> 5) * 64;
        int cc = tid & 63, rq = tid >> 6;
        #pragma unroll
        for (int r = 0; r < 16; ++r) {
            int rr = r * 4 + rq;
            tile[rr * 65 + cc] = wo[(size_t)(r0 + rr) * 2048 + d0 + cc];
        }
        __syncthreads();
        #pragma unroll
        for (int r = 0; r < 16; ++r) {
            int rr = r * 4 + rq;
            wt_o[(size_t)(d0 + rr) * 2048 + r0 + cc] = f2bf(tile[cc * 65 + rr]);
        }
    }
}

// ---------------- 8-phase 256x256 GEMM, deep-prefetch schedule (r7 proven; FROZEN) ----------------

__global__ __launch_bounds__(512, 2)
void gemm8p(const unsigned short* __restrict__ A,
            const unsigned short* __restrict__ Bt,
            unsigned short* __restrict__ C,
            int ldk, int ldc, int nt, int ksplit, size_t cstride) {
    __shared__ __align__(16) unsigned short LDS[65536];
    const int tid = threadIdx.x, lane = tid & 63, w = tid >> 6;
    const int wr = w >> 2, wc = w & 3;
    const int l15 = lane & 15, l4 = lane >> 4;
    int nwg = gridDim.x * gridDim.y;
    int wg = blockIdx.y * gridDim.x + blockIdx.x;
    int swz = (wg & 7) * (nwg >> 3) + (wg >> 3);
    int bx = swz % gridDim.x, by = swz / gridDim.x;
    int slice = 0;
    if (ksplit) { slice = by & 1; by >>= 1; }
    unsigned short* Cs = C + (size_t)slice * cstride;
    const int brow = by * 256, bcol = bx * 256;
    const size_t koff = (size_t)slice * nt * 64;
    const int wg_a = w & 3;
    const int wg_b = wr;
    const int rA = wg_a * 8 + (lane >> 3);
    const int rB = wg_b * 8 + (lane >> 3);
    const int cgS = ((lane & 7) ^ (lane >> 3)) * 8;
    const unsigned short* aP = A + (size_t)(brow + wr * 128 + rA) * ldk + koff + cgS;
    const unsigned short* bP = Bt + (size_t)(bcol + wc * 64 + rB) * ldk + koff + cgS;
    const int ldsA0 = wr * 8192 + (wg_a * 64 + lane) * 8;
    const int ldsB0 = wc * 4096 + (wg_b * 64 + lane) * 8;
    const int aRd = (wr * 128 + l15) * 64;
    const int bRd = (wc * 64 + l15) * 64;
    const int c0 = ((0 + l4) ^ (l15 & 7)) * 8;
    const int c1 = ((4 + l4) ^ (l15 & 7)) * 8;
    f32x4 acc[8][4] = {};
    gload_lds16(aP,                    &LDS[ldsA0]);
    gload_lds16(bP,                    &LDS[16384 + ldsB0]);
    gload_lds16(aP + (size_t)32 * ldk, &LDS[ldsA0 + 2048]);
    gload_lds16(bP + (size_t)16 * ldk, &LDS[16384 + ldsB0 + 1024]);
    gload_lds16(bP + (size_t)32 * ldk, &LDS[16384 + ldsB0 + 2048]);
    gload_lds16(bP + (size_t)48 * ldk, &LDS[16384 + ldsB0 + 3072]);
    gload_lds16(aP + (size_t)64 * ldk, &LDS[ldsA0 + 4096]);
    gload_lds16(aP + (size_t)96 * ldk, &LDS[ldsA0 + 6144]);
    {
        const unsigned short* a1 = aP + 64;
        const unsigned short* b1 = bP + 64;
        gload_lds16(a1,                    &LDS[32768 + ldsA0]);
        gload_lds16(b1,                    &LDS[49152 + ldsB0]);
        gload_lds16(a1 + (size_t)32 * ldk, &LDS[32768 + ldsA0 + 2048]);
        gload_lds16(b1 + (size_t)16 * ldk, &LDS[49152 + ldsB0 + 1024]);
        gload_lds16(b1 + (size_t)32 * ldk, &LDS[49152 + ldsB0 + 2048]);
        gload_lds16(b1 + (size_t)48 * ldk, &LDS[49152 + ldsB0 + 3072]);
    }
    asm volatile("s_waitcnt vmcnt(6)" ::: "memory");
    __builtin_amdgcn_s_barrier();
    __builtin_amdgcn_sched_barrier(0);

    short8 af[4][2], bl[2][2], bh[2][2];
    for (int t = 0; t < nt - 1; ++t) {
        const int bufA = (t & 1) << 15, bufB = bufA + 16384;
        const int sA = ((t + 1) & 1) << 15;
        const bool pf2 = (t + 2) < nt;
        const unsigned short* ap1 = aP + (size_t)(t + 1) * 64;
        const unsigned short* ap2 = aP + (size_t)(t + 2) * 64;
        const unsigned short* bp2 = bP + (size_t)(t + 2) * 64;
        #pragma unroll
        for (int m = 0; m < 4; ++m) {
            af[m][0] = *(const short8*)&LDS[bufA + aRd + m * 1024 + c0];
            af[m][1] = *(const short8*)&LDS[bufA + aRd + m * 1024 + c1];
        }
        #pragma unroll
        for (int n = 0; n < 2; ++n) {
            bl[n][0] = *(const short8*)&LDS[bufB + bRd + n * 1024 + c0];
            bl[n][1] = *(const short8*)&LDS[bufB + bRd + n * 1024 + c1];
        }
        gload_lds16(ap1 + (size_t)64 * ldk, &LDS[sA + ldsA0 + 4096]);
        gload_lds16(ap1 + (size_t)96 * ldk, &LDS[sA + ldsA0 + 6144]);
        __builtin_amdgcn_s_barrier();
        __builtin_amdgcn_sched_barrier(0);
        __builtin_amdgcn_s_setprio(1);
        #pragma unroll
        for (int kk = 0; kk < 2; ++kk)
            #pragma unroll
            for (int m = 0; m < 4; ++m)
                #pragma unroll
                for (int n = 0; n < 2; ++n)
                    acc[m][n] = MFMA_B16(af[m][kk], bl[n][kk], acc[m][n], 0, 0, 0);
        __builtin_amdgcn_s_setprio(0);
        asm volatile("s_waitcnt vmcnt(6)" ::: "memory");
        __builtin_amdgcn_s_barrier();
        __builtin_amdgcn_sched_barrier(0);
        #pragma unroll
        for (int n = 0; n < 2; ++n) {
            bh[n][0] = *(const short8*)&LDS[bufB + bRd + (n + 2) * 1024 + c0];
            bh[n][1] = *(const short8*)&LDS[bufB + bRd + (n + 2) * 1024 + c1];
        }
        if (pf2) { gload_lds16(ap2, &LDS[bufA + ldsA0]);
                   gload_lds16(bp2, &LDS[bufB + ldsB0]); }
        __builtin_amdgcn_s_barrier();
        __builtin_amdgcn_sched_barrier(0);
        __builtin_amdgcn_s_setprio(1);
        #pragma unroll
        for (int kk = 0; kk < 2; ++kk)
            #pragma unroll
            for (int m = 0; m < 4; ++m)
                #pragma unroll
                for (int n = 0; n < 2; ++n)
                    acc[m][n + 2] = MFMA_B16(af[m][kk], bh[n][kk], acc[m][n + 2], 0, 0, 0);
        __builtin_amdgcn_s_setprio(0);
        asm volatile("s_waitcnt vmcnt(6)" ::: "memory");
        __builtin_amdgcn_s_barrier();
        __builtin_amdgcn_sched_barrier(0);
        #pragma unroll
        for (int m = 0; m < 4; ++m) {
            af[m][0] = *(const short8*)&LDS[bufA + aRd + (m + 4) * 1024 + c0];
            af[m][1] = *(const short8*)&LDS[bufA + aRd + (m + 4) * 1024 + c1];
        }
        if (pf2) { gload_lds16(ap2 + (size_t)32 * ldk, &LDS[bufA + ldsA0 + 2048]);
                   gload_lds16(bp2 + (size_t)16 * ldk, &LDS[bufB + ldsB0 + 1024]); }
        __builtin_amdgcn_s_barrier();
        __builtin_amdgcn_sched_barrier(0);
        __builtin_amdgcn_s_setprio(1);
        #pragma unroll
        for (int kk = 0; kk < 2; ++kk)
            #pragma unroll
            for (int m = 0; m < 4; ++m)
                #pragma unroll
                for (int n = 0; n < 2; ++n)
                    acc[m + 4][n] = MFMA_B16(af[m][kk], bl[n][kk], acc[m + 4][n], 0, 0, 0);
        __builtin_amdgcn_s_setprio(0);
        asm volatile("s_waitcnt vmcnt(6)" ::: "memory");
        __builtin_amdgcn_s_barrier();
        __builtin_amdgcn_sched_barrier(0);
        if (pf2) { gload_lds16(bp2 + (size_t)32 * ldk, &LDS[bufB + ldsB0 + 2048]);
                   gload_lds16(bp2 + (size_t)48 * ldk, &LDS[bufB + ldsB0 + 3072]); }
        __builtin_amdgcn_s_barrier();
        __builtin_amdgcn_sched_barrier(0);
        __builtin_amdgcn_s_setprio(1);
        #pragma unroll
        for (int kk = 0; kk < 2; ++kk)
            #pragma unroll
            for (int m = 0; m < 4; ++m)
                #pragma unroll
                for (int n = 0; n < 2; ++n)
                    acc[m + 4][n + 2] = MFMA_B16(af[m][kk], bh[n][kk], acc[m + 4][n + 2], 0, 0, 0);
        __builtin_amdgcn_s_setprio(0);
        asm volatile("s_waitcnt vmcnt(6)" ::: "memory");
        __builtin_amdgcn_s_barrier();
        __builtin_amdgcn_sched_barrier(0);
    }
    asm volatile("s_waitcnt vmcnt(0)" ::: "memory");
    __builtin_amdgcn_s_barrier();
    {
        const int bufA = ((nt - 1) & 1) << 15, bufB = bufA + 16384;
        #pragma unroll
        for (int m = 0; m < 4; ++m) {
            af[m][0] = *(const short8*)&LDS[bufA + aRd + m * 1024 + c0];
            af[m][1] = *(const short8*)&LDS[bufA + aRd + m * 1024 + c1];
        }
        #pragma unroll
        for (int n = 0; n < 2; ++n) {
            bl[n][0] = *(const short8*)&LDS[bufB + bRd + n * 1024 + c0];
            bl[n][1] = *(const short8*)&LDS[bufB + bRd + n * 1024 + c1];
            bh[n][0] = *(const short8*)&LDS[bufB + bRd + (n + 2) * 1024 + c0];
            bh[n][1] = *(const short8*)&LDS[bufB + bRd + (n + 2) * 1024 + c1];
        }
        #pragma unroll
        for (int kk = 0; kk < 2; ++kk)
            #pragma unroll
            for (int m = 0; m < 4; ++m)
                #pragma unroll
                for (int n = 0; n < 2; ++n) {
                    acc[m][n]     = MFMA_B16(af[m][kk], bl[n][kk], acc[m][n], 0, 0, 0);
                    acc[m][n + 2] = MFMA_B16(af[m][kk], bh[n][kk], acc[m][n + 2], 0, 0, 0);
                }
        #pragma unroll
        for (int m = 0; m < 4; ++m) {
            af[m][0] = *(const short8*)&LDS[bufA + aRd + (m + 4) * 1024 + c0];
            af[m][1] = *(const short8*)&LDS[bufA + aRd + (m + 4) * 1024 + c1];
        }
        #pragma unroll
        for (int kk = 0; kk < 2; ++kk)
            #pragma unroll
            for (int m = 0; m < 4; ++m)
                #pragma unroll
                for (int n = 0; n < 2; ++n) {
                    acc[m + 4][n]     = MFMA_B16(af[m][kk], bl[n][kk], acc[m + 4][n], 0, 0, 0);
                    acc[m + 4][n + 2] = MFMA_B16(af[m][kk], bh[n][kk], acc[m + 4][n + 2], 0, 0, 0);
                }
    }
    #pragma unroll
    for (int m = 0; m < 8; ++m)
        #pragma unroll
        for (int n = 0; n < 4; ++n)
            #pragma unroll
            for (int j = 0; j < 4; ++j) {
                int row = brow + wr * 128 + m * 16 + l4 * 4 + j;
                int col = bcol + wc * 64 + n * 16 + l15;
                Cs[(size_t)row * ldc + col] = f2bf(acc[m][n][j]);
            }
}

// ---------------- split-K reduce ----------------
__global__ void addparts(const unsigned short* __restrict__ p0,
                         const unsigned short* __restrict__ p1,
                         float* __restrict__ out) {
    int i = blockIdx.x * 256 + threadIdx.x;
    short8 a = ((const short8*)p0)[i];
    short8 b = ((const short8*)p1)[i];
    f4 lo, hi;
    #pragma unroll
    for (int j = 0; j < 4; ++j)
        lo[j] = bf2f((unsigned short)a[j]) + bf2f((unsigned short)b[j]);
    #pragma unroll
    for (int j = 0; j < 4; ++j)
        hi[j] = bf2f((unsigned short)a[j + 4]) + bf2f((unsigned short)b[j + 4]);
    ((f4*)out)[2 * i] = lo;
    ((f4*)out)[2 * i + 1] = hi;
}

// ---------------- merged RoPE + V transpose (one launch) ----------------
__global__ void rope_vt(const unsigned short* __restrict__ qkv,
                        const int* __restrict__ segpos,
                        unsigned short* __restrict__ q_r,
                        unsigned short* __restrict__ k_r,
                        unsigned short* __restrict__ v_t) {
    __shared__ unsigned short tile[64][72];
    const int bx = blockIdx.x, tid = threadIdx.x;
    if (bx < 49152) {
        const int bt = bx & 4095;
        const int hd = (bx >> 12) * 2 + (tid >> 7);
        const int b = bt >> 11, t = bt & 2047;
        const int h = tid & 127;
        const unsigned short* in = (hd < 16)
            ? qkv + (size_t)bt * 4096 + hd * 128
            : qkv + (size_t)bt * 4096 + 2048 + (hd - 16) * 128;
        int pos = segpos[bt];
        int i = h & 63;
        float inv_ts = __expf((float)i * (-9.210340371976184f / 64.f));
        float ang = (float)pos * inv_ts;
        float s = __sinf(ang), c = __cosf(ang);
        float x1 = bf2f(in[i]);
        float x2 = bf2f(in[i + 64]);
        float o = (h < 64) ? (x1 * c - x2 * s) : (x2 * c + x1 * s);
        if (hd < 16) {
            q_r[((size_t)((b * 16 + hd) * 2048 + t)) * 128 + h] = f2bf(o);
        } else {
            int kh = hd - 16;
            k_r[((size_t)((b * 8 + kh) * 2048 + t)) * 128 + h] = f2bf(o);
        }
        return;
    }
    {
        const int flat = bx - 49152;
        const int tt0 = (flat & 31) * 64;
        const int y = (flat >> 5) & 15;
        const int b = flat >> 9;
        const int kh = y >> 1, hb = (y & 1) * 64;
        int c = tid & 63, rq = tid >> 6;
        #pragma unroll
        for (int r = 0; r < 16; ++r) {
            int tt = r * 4 + rq;
            tile[tt][c] = qkv[(size_t)(b * 2048 + tt0 + tt) * 4096 + 3072 + kh * 128 + hb + c];
        }
        __syncthreads();
        #pragma unroll
        for (int r = 0; r < 16; ++r) {
            int hr = r * 4 + rq;
            v_t[((size_t)(b * 8 + kh) * 128 + hb + hr) * 2048 + tt0 + c] = tile[c][hr];
        }
    }
}

// ---------------- flash attention, KVBLK=32 (4 blocks/CU; fixed-max softmax; ones-MFMA l) ----------------
// LDS 40KB: Ks 2x8K, Vt 2x8K, Pl 4x2K (wave-pairs share 64-col rows, disjoint 32-col halves
// under the row-XOR swizzle). V conflict-free via granule^=(row>>1)&3 (2-way, free).

__device__ __forceinline__ void stage_kv32(const unsigned short* kbase, const unsigned short* vbase,
                                           unsigned short* Ksb, unsigned short* Vtb,
                                           int st, int tid) {
    int e = tid * 8;
    int krow = tid >> 4, kcol = e & 127;                 // K[32][128]
    gload_lds16(kbase + (size_t)(st * 32 + krow) * 128 + (kcol ^ ((krow & 7) << 3)), Ksb + e);
    int vrow = tid >> 2, vg = tid & 3;                   // V[128][32], 4 granules of 8
    gload_lds16(vbase + (size_t)vrow * 2048 + st * 32 + ((vg ^ ((vrow >> 1) & 3)) * 8), Vtb + e);
}

__global__ __launch_bounds__(512, 4)
void attn_kernel(const unsigned short* __restrict__ q_r,
                 const unsigned short* __restrict__ k_r,
                 const unsigned short* __restrict__ v_t,
                 unsigned short* __restrict__ enc) {
    __shared__ __align__(16) unsigned short Ks[2][32 * 128];
    __shared__ __align__(16) unsigned short Vt[2][128 * 32];
    __shared__ __align__(16) unsigned short Pl[4][16 * 64];
    const int tid = threadIdx.x, lane = tid & 63, wave = tid >> 6;
    const int l15 = lane & 15, l4 = lane >> 4;
    const int flat = blockIdx.x;
    const int xcd = flat & 7, g = flat >> 3;
    const int pair = xcd * 2 + (g >> 5);
    const int qb = (g & 32) ? (g & 31) : 31 - (g & 31);   // complementary CU pairing
    const int kh = pair >> 1, b = pair & 1;
    const int n = kh * 2 + (wave >> 2);
    const int wq = wave & 3;
    const int colbase = (wave & 1) * 32;                  // this wave's half of the shared P row
    unsigned short* Plb = Pl[wave >> 1];
    short8 qf[4];
    {
        const unsigned short* qp =
            q_r + ((size_t)((b * 16 + n) * 2048 + qb * 64 + wq * 16 + l15)) * 128 + l4 * 8;
        #pragma unroll
        for (int kk = 0; kk < 4; ++kk) qf[kk] = *(const short8*)(qp + kk * 32);
    }
    short8 ones;
    #pragma unroll
    for (int e = 0; e < 8; ++e) ones[e] = (short)0x3F80;  // bf16 1.0
    f32x4 Of[8] = {};
    f32x4 accl = {};
    int t_lo = qb * 64 - 1023; if (t_lo < 0) t_lo = 0;
    const int st0 = t_lo >> 5;
    const int stL = qb * 2 + 1;
    const unsigned short* kbase = k_r + (size_t)(b * 8 + kh) * 2048 * 128;
    const unsigned short* vbase = v_t + (size_t)(b * 8 + kh) * 128 * 2048;

    stage_kv32(kbase, vbase, Ks[0], Vt[0], st0, tid);
    __syncthreads();
    int cur = 0;
    for (int st = st0; st <= stL; ++st) {
        if (st < stL)
            stage_kv32(kbase, vbase, Ks[cur ^ 1], Vt[cur ^ 1], st + 1, tid);
        // ---- QK^T (16 rows x 32 cols) ----
        f32x4 sf[2] = {};
        __builtin_amdgcn_s_setprio(1);
        #pragma unroll
        for (int nc = 0; nc < 2; ++nc) {
            int row = nc * 16 + l15;
            int sw = (l15 & 7) << 3;
            #pragma unroll
            for (int kk = 0; kk < 4; ++kk) {
                short8 bfr = *(const short8*)&Ks[cur][row * 128 + ((kk * 32 + l4 * 8) ^ sw)];
                sf[nc] = MFMA_B16(qf[kk], bfr, sf[nc], 0, 0, 0);
            }
        }
        __builtin_amdgcn_s_setprio(0);
        // ---- softcap+softmax: sf pre-scaled by log2e/25; p = 2^(-144.27/(2^sf+1)) ----
        const int mode = ((st >= 2 * qb) ? 1 : 0) | ((qb >= 16 && st <= st0 + 1) ? 2 : 0);
        #pragma unroll
        for (int j = 0; j < 4; ++j) {
            int trow = qb * 64 + wq * 16 + l4 * 4 + j;
            int prow = l4 * 4 + j;
            int psw = (prow & 7) << 3;
            float pp[2];
            #pragma unroll
            for (int nc = 0; nc < 2; ++nc) {
                float ex = fexp2(sf[nc][j]);
                float p = fexp2(-144.26950408889634f * __builtin_amdgcn_rcpf(ex + 1.f));
                if (mode) {
                    int s = st * 32 + nc * 16 + l15;
                    bool ok = true;
                    if (mode & 1) ok = ok && (s <= trow);
                    if (mode & 2) ok = ok && (s >= trow - 1023);
                    p = ok ? p : 0.f;
                }
                pp[nc] = p;
            }
            unsigned int k01 = cvt_pk_bf16(pp[0], pp[1]);
            unsigned short* Pr = &Plb[prow * 64];
            Pr[(colbase + l15) ^ psw]      = (unsigned short)k01;
            Pr[(colbase + 16 + l15) ^ psw] = (unsigned short)(k01 >> 16);
        }
        // ---- PV + row-sum (ones-MFMA) ----
        {
            int asw = (l15 & 7) << 3;
            __builtin_amdgcn_s_setprio(1);
            short8 af = *(const short8*)&Plb[l15 * 64 + ((colbase + l4 * 8) ^ asw)];
            accl = MFMA_B16(af, ones, accl, 0, 0, 0);
            #pragma unroll
            for (int hc = 0; hc < 8; ++hc) {
                int vrow = hc * 16 + l15;
                short8 bfr = *(const short8*)&Vt[cur][vrow * 32 + ((l4 ^ ((vrow >> 1) & 3)) * 8)];
                Of[hc] = MFMA_B16(af, bfr, Of[hc], 0, 0, 0);
            }
            __builtin_amdgcn_s_setprio(0);
        }
        __syncthreads();
        cur ^= 1;
    }
    f32x4 inv;
    #pragma unroll
    for (int j = 0; j < 4; ++j) inv[j] = 1.f / accl[j];
    #pragma unroll
    for (int hc = 0; hc < 8; ++hc)
        #pragma unroll
        for (int j = 0; j < 4; ++j) {
            size_t row = (size_t)(b * 2048 + qb * 64 + wq * 16 + l4 * 4 + j);
            enc[row * 2048 + n * 128 + hc * 16 + l15] = f2bf(Of[hc][j] * inv[j]);
        }
}

// ---------------- launch ----------------

extern "C" void kernel_launch(void* const* d_in, const int* in_sizes, int n_in,
                              void* d_out, int out_size, void* d_ws, size_t ws_size,
                              hipStream_t stream) {
    const float* x   = (const float*)d_in[0];
    const int* segp  = (const int*)d_in[1];
    const float* wq  = (const float*)d_in[3];
    const float* wkv = (const float*)d_in[4];
    const float* wo  = (const float*)d_in[5];
    float* out = (float*)d_out;
    char* ws = (char*)d_ws;
    if (ws_size < ((size_t)104 << 20)) return;

    unsigned short* xb    = (unsigned short*)(ws);                       // [0,16) MiB
    unsigned short* wqkvt = (unsigned short*)(ws + ((size_t)16 << 20));  // [16,32)
    unsigned short* qkv   = (unsigned short*)(ws + ((size_t)32 << 20));  // [32,64)
    unsigned short* q_r   = (unsigned short*)(ws + ((size_t)64 << 20));  // [64,80)
    unsigned short* k_r   = (unsigned short*)(ws + ((size_t)80 << 20));  // [80,88)
    unsigned short* v_t   = (unsigned short*)(ws + ((size_t)88 << 20));  // [88,96)
    unsigned short* wo_t  = (unsigned short*)(ws + ((size_t)96 << 20));  // [96,104)
    unsigned short* enc   = (unsigned short*)(ws + ((size_t)32 << 20));  // reuse qkv
    unsigned short* part  = (unsigned short*)(ws + ((size_t)64 << 20));  // reuse q_r/k_r/v_t

    conv_all<<<11264, 256, 0, stream>>>(x, xb, wq, wkv, wqkvt, wo, wo_t);
    gemm8p<<<dim3(16, 16), 512, 0, stream>>>(xb, wqkvt, qkv, 2048, 4096, 32, 0, 0);
    rope_vt<<<50176, 256, 0, stream>>>(qkv, segp, q_r, k_r, v_t);
    attn_kernel<<<512, 512, 0, stream>>>(q_r, k_r, v_t, enc);
    gemm8p<<<dim3(8, 32), 512, 0, stream>>>(enc, wo_t, part, 2048, 2048, 16, 1, (size_t)4096 * 2048);
    addparts<<<4096, 256, 0, stream>>>(part, part + (size_t)4096 * 2048, out);
}

// Round 14
// 204.885 us; speedup vs baseline: 1.0073x; 1.0073x over previous
//
#include <hip/hip_runtime.h>

typedef __attribute__((ext_vector_type(8))) short short8;
typedef __attribute__((ext_vector_type(4))) float f32x4;
typedef __attribute__((ext_vector_type(4))) float f4;
typedef __attribute__((ext_vector_type(4))) unsigned short u16x4;

#define MFMA_B16 __builtin_amdgcn_mfma_f32_16x16x32_bf16

__device__ __forceinline__ unsigned short f2bf(float f) {
    union { float f; unsigned int u; } v; v.f = f;
    unsigned int r = v.u + 0x7fffu + ((v.u >> 16) & 1u);
    return (unsigned short)(r >> 16);
}
__device__ __forceinline__ float bf2f(unsigned short h) {
    union { unsigned int u; float f; } v; v.u = ((unsigned int)h) << 16;
    return v.f;
}
__device__ __forceinline__ float fexp2(float x) {
    float r; asm("v_exp_f32 %0, %1" : "=v"(r) : "v"(x)); return r;
}
__device__ __forceinline__ unsigned int cvt_pk_bf16(float lo, float hi) {
    unsigned int r;
    asm("v_cvt_pk_bf16_f32 %0, %1, %2" : "=v"(r) : "v"(lo), "v"(hi));
    return r;
}
__device__ __forceinline__ void gload_lds16(const void* g, void* l) {
    __builtin_amdgcn_global_load_lds(
        (const __attribute__((address_space(1))) unsigned int*)g,
        (__attribute__((address_space(3))) unsigned int*)l, 16, 0, 0);
}

// ---------------- merged conversions (one launch) ----------------
__global__ void conv_all(const float* __restrict__ x, unsigned short* __restrict__ xb,
                         const float* __restrict__ wq, const float* __restrict__ wkv,
                         unsigned short* __restrict__ wt_qkv,
                         const float* __restrict__ wo, unsigned short* __restrict__ wt_o) {
    __shared__ float tile[64 * 65];
    const int bx = blockIdx.x, tid = threadIdx.x;
    if (bx < 8192) {
        int i = bx * 256 + tid;
        f4 v = ((const f4*)x)[i];
        u16x4 o;
        o[0] = f2bf(v[0]); o[1] = f2bf(v[1]); o[2] = f2bf(v[2]); o[3] = f2bf(v[3]);
        ((u16x4*)xb)[i] = o;
        return;
    }
    if (bx < 10240) {
        const int flat = bx - 8192;
        const int d0 = (flat & 31) * 64, f0 = (flat >> 5) * 64;
        const int head = f0 >> 7;
        const int h0 = f0 & 127;
        const float* src;
        float scl;
        if (head < 16)      { src = wq + (size_t)head * 2048 * 128;         scl = 0.08838834764831845f; }
        else if (head < 24) { src = wkv + (size_t)(head - 16) * 2048 * 128; scl = 0.057707801635558534f; }
        else                { src = wkv + (size_t)(head - 16) * 2048 * 128; scl = 1.f; }
        {
            int hh = tid & 63, dq = tid >> 6;
            #pragma unroll
            for (int r = 0; r < 16; ++r) {
                int dd = r * 4 + dq;
                tile[dd * 65 + hh] = src[(size_t)(d0 + dd) * 128 + h0 + hh] * scl;
            }
        }
        __syncthreads();
        {
            int dd = tid & 63, fq = tid >> 6;
            #pragma unroll
            for (int r = 0; r < 16; ++r) {
                int fl = r * 4 + fq;
                wt_qkv[(size_t)(f0 + fl) * 2048 + d0 + dd] = f2bf(tile[dd * 65 + fl]);
            }
        }
        return;
    }
    {
        const int flat = bx - 10240;
        const int d0 = (flat & 31) * 64, r0 = (flat >> 5) * 64;
        int cc = tid & 63, rq = tid >> 6;
        #pragma unroll
        for (int r = 0; r < 16; ++r) {
            int rr = r * 4 + rq;
            tile[rr * 65 + cc] = wo[(size_t)(r0 + rr) * 2048 + d0 + cc];
        }
        __syncthreads();
        #pragma unroll
        for (int r = 0; r < 16; ++r) {
            int rr = r * 4 + rq;
            wt_o[(size_t)(d0 + rr) * 2048 + r0 + cc] = f2bf(tile[cc * 65 + rr]);
        }
    }
}

// ---------------- 8-phase 256x256 GEMM, deep-prefetch schedule (r7 proven; FROZEN) ----------------

__global__ __launch_bounds__(512, 2)
void gemm8p(const unsigned short* __restrict__ A,
            const unsigned short* __restrict__ Bt,
            unsigned short* __restrict__ C,
            int ldk, int ldc, int nt, int ksplit, size_t cstride) {
    __shared__ __align__(16) unsigned short LDS[65536];
    const int tid = threadIdx.x, lane = tid & 63, w = tid >> 6;
    const int wr = w >> 2, wc = w & 3;
    const int l15 = lane & 15, l4 = lane >> 4;
    int nwg = gridDim.x * gridDim.y;
    int wg = blockIdx.y * gridDim.x + blockIdx.x;
    int swz = (wg & 7) * (nwg >> 3) + (wg >> 3);
    int bx = swz % gridDim.x, by = swz / gridDim.x;
    int slice = 0;
    if (ksplit) { slice = by & 1; by >>= 1; }
    unsigned short* Cs = C + (size_t)slice * cstride;
    const int brow = by * 256, bcol = bx * 256;
    const size_t koff = (size_t)slice * nt * 64;
    const int wg_a = w & 3;
    const int wg_b = wr;
    const int rA = wg_a * 8 + (lane >> 3);
    const int rB = wg_b * 8 + (lane >> 3);
    const int cgS = ((lane & 7) ^ (lane >> 3)) * 8;
    const unsigned short* aP = A + (size_t)(brow + wr * 128 + rA) * ldk + koff + cgS;
    const unsigned short* bP = Bt + (size_t)(bcol + wc * 64 + rB) * ldk + koff + cgS;
    const int ldsA0 = wr * 8192 + (wg_a * 64 + lane) * 8;
    const int ldsB0 = wc * 4096 + (wg_b * 64 + lane) * 8;
    const int aRd = (wr * 128 + l15) * 64;
    const int bRd = (wc * 64 + l15) * 64;
    const int c0 = ((0 + l4) ^ (l15 & 7)) * 8;
    const int c1 = ((4 + l4) ^ (l15 & 7)) * 8;
    f32x4 acc[8][4] = {};
    gload_lds16(aP,                    &LDS[ldsA0]);
    gload_lds16(bP,                    &LDS[16384 + ldsB0]);
    gload_lds16(aP + (size_t)32 * ldk, &LDS[ldsA0 + 2048]);
    gload_lds16(bP + (size_t)16 * ldk, &LDS[16384 + ldsB0 + 1024]);
    gload_lds16(bP + (size_t)32 * ldk, &LDS[16384 + ldsB0 + 2048]);
    gload_lds16(bP + (size_t)48 * ldk, &LDS[16384 + ldsB0 + 3072]);
    gload_lds16(aP + (size_t)64 * ldk, &LDS[ldsA0 + 4096]);
    gload_lds16(aP + (size_t)96 * ldk, &LDS[ldsA0 + 6144]);
    {
        const unsigned short* a1 = aP + 64;
        const unsigned short* b1 = bP + 64;
        gload_lds16(a1,                    &LDS[32768 + ldsA0]);
        gload_lds16(b1,                    &LDS[49152 + ldsB0]);
        gload_lds16(a1 + (size_t)32 * ldk, &LDS[32768 + ldsA0 + 2048]);
        gload_lds16(b1 + (size_t)16 * ldk, &LDS[49152 + ldsB0 + 1024]);
        gload_lds16(b1 + (size_t)32 * ldk, &LDS[49152 + ldsB0 + 2048]);
        gload_lds16(b1 + (size_t)48 * ldk, &LDS[49152 + ldsB0 + 3072]);
    }
    asm volatile("s_waitcnt vmcnt(6)" ::: "memory");
    __builtin_amdgcn_s_barrier();
    __builtin_amdgcn_sched_barrier(0);

    short8 af[4][2], bl[2][2], bh[2][2];
    for (int t = 0; t < nt - 1; ++t) {
        const int bufA = (t & 1) << 15, bufB = bufA + 16384;
        const int sA = ((t + 1) & 1) << 15;
        const bool pf2 = (t + 2) < nt;
        const unsigned short* ap1 = aP + (size_t)(t + 1) * 64;
        const unsigned short* ap2 = aP + (size_t)(t + 2) * 64;
        const unsigned short* bp2 = bP + (size_t)(t + 2) * 64;
        #pragma unroll
        for (int m = 0; m < 4; ++m) {
            af[m][0] = *(const short8*)&LDS[bufA + aRd + m * 1024 + c0];
            af[m][1] = *(const short8*)&LDS[bufA + aRd + m * 1024 + c1];
        }
        #pragma unroll
        for (int n = 0; n < 2; ++n) {
            bl[n][0] = *(const short8*)&LDS[bufB + bRd + n * 1024 + c0];
            bl[n][1] = *(const short8*)&LDS[bufB + bRd + n * 1024 + c1];
        }
        gload_lds16(ap1 + (size_t)64 * ldk, &LDS[sA + ldsA0 + 4096]);
        gload_lds16(ap1 + (size_t)96 * ldk, &LDS[sA + ldsA0 + 6144]);
        __builtin_amdgcn_s_barrier();
        __builtin_amdgcn_sched_barrier(0);
        __builtin_amdgcn_s_setprio(1);
        #pragma unroll
        for (int kk = 0; kk < 2; ++kk)
            #pragma unroll
            for (int m = 0; m < 4; ++m)
                #pragma unroll
                for (int n = 0; n < 2; ++n)
                    acc[m][n] = MFMA_B16(af[m][kk], bl[n][kk], acc[m][n], 0, 0, 0);
        __builtin_amdgcn_s_setprio(0);
        asm volatile("s_waitcnt vmcnt(6)" ::: "memory");
        __builtin_amdgcn_s_barrier();
        __builtin_amdgcn_sched_barrier(0);
        #pragma unroll
        for (int n = 0; n < 2; ++n) {
            bh[n][0] = *(const short8*)&LDS[bufB + bRd + (n + 2) * 1024 + c0];
            bh[n][1] = *(const short8*)&LDS[bufB + bRd + (n + 2) * 1024 + c1];
        }
        if (pf2) { gload_lds16(ap2, &LDS[bufA + ldsA0]);
                   gload_lds16(bp2, &LDS[bufB + ldsB0]); }
        __builtin_amdgcn_s_barrier();
        __builtin_amdgcn_sched_barrier(0);
        __builtin_amdgcn_s_setprio(1);
        #pragma unroll
        for (int kk = 0; kk < 2; ++kk)
            #pragma unroll
            for (int m = 0; m < 4; ++m)
                #pragma unroll
                for (int n = 0; n < 2; ++n)
                    acc[m][n + 2] = MFMA_B16(af[m][kk], bh[n][kk], acc[m][n + 2], 0, 0, 0);
        __builtin_amdgcn_s_setprio(0);
        asm volatile("s_waitcnt vmcnt(6)" ::: "memory");
        __builtin_amdgcn_s_barrier();
        __builtin_amdgcn_sched_barrier(0);
        #pragma unroll
        for (int m = 0; m < 4; ++m) {
            af[m][0] = *(const short8*)&LDS[bufA + aRd + (m + 4) * 1024 + c0];
            af[m][1] = *(const short8*)&LDS[bufA + aRd + (m + 4) * 1024 + c1];
        }
        if (pf2) { gload_lds16(ap2 + (size_t)32 * ldk, &LDS[bufA + ldsA0 + 2048]);
                   gload_lds16(bp2 + (size_t)16 * ldk, &LDS[bufB + ldsB0 + 1024]); }
        __builtin_amdgcn_s_barrier();
        __builtin_amdgcn_sched_barrier(0);
        __builtin_amdgcn_s_setprio(1);
        #pragma unroll
        for (int kk = 0; kk < 2; ++kk)
            #pragma unroll
            for (int m = 0; m < 4; ++m)
                #pragma unroll
                for (int n = 0; n < 2; ++n)
                    acc[m + 4][n] = MFMA_B16(af[m][kk], bl[n][kk], acc[m + 4][n], 0, 0, 0);
        __builtin_amdgcn_s_setprio(0);
        asm volatile("s_waitcnt vmcnt(6)" ::: "memory");
        __builtin_amdgcn_s_barrier();
        __builtin_amdgcn_sched_barrier(0);
        if (pf2) { gload_lds16(bp2 + (size_t)32 * ldk, &LDS[bufB + ldsB0 + 2048]);
                   gload_lds16(bp2 + (size_t)48 * ldk, &LDS[bufB + ldsB0 + 3072]); }
        __builtin_amdgcn_s_barrier();
        __builtin_amdgcn_sched_barrier(0);
        __builtin_amdgcn_s_setprio(1);
        #pragma unroll
        for (int kk = 0; kk < 2; ++kk)
            #pragma unroll
            for (int m = 0; m < 4; ++m)
                #pragma unroll
                for (int n = 0; n < 2; ++n)
                    acc[m + 4][n + 2] = MFMA_B16(af[m][kk], bh[n][kk], acc[m + 4][n + 2], 0, 0, 0);
        __builtin_amdgcn_s_setprio(0);
        asm volatile("s_waitcnt vmcnt(6)" ::: "memory");
        __builtin_amdgcn_s_barrier();
        __builtin_amdgcn_sched_barrier(0);
    }
    asm volatile("s_waitcnt vmcnt(0)" ::: "memory");
    __builtin_amdgcn_s_barrier();
    {
        const int bufA = ((nt - 1) & 1) << 15, bufB = bufA + 16384;
        #pragma unroll
        for (int m = 0; m < 4; ++m) {
            af[m][0] = *(const short8*)&LDS[bufA + aRd + m * 1024 + c0];
            af[m][1] = *(const short8*)&LDS[bufA + aRd + m * 1024 + c1];
        }
        #pragma unroll
        for (int n = 0; n < 2; ++n) {
            bl[n][0] = *(const short8*)&LDS[bufB + bRd + n * 1024 + c0];
            bl[n][1] = *(const short8*)&LDS[bufB + bRd + n * 1024 + c1];
            bh[n][0] = *(const short8*)&LDS[bufB + bRd + (n + 2) * 1024 + c0];
            bh[n][1] = *(const short8*)&LDS[bufB + bRd + (n + 2) * 1024 + c1];
        }
        #pragma unroll
        for (int kk = 0; kk < 2; ++kk)
            #pragma unroll
            for (int m = 0; m < 4; ++m)
                #pragma unroll
                for (int n = 0; n < 2; ++n) {
                    acc[m][n]     = MFMA_B16(af[m][kk], bl[n][kk], acc[m][n], 0, 0, 0);
                    acc[m][n + 2] = MFMA_B16(af[m][kk], bh[n][kk], acc[m][n + 2], 0, 0, 0);
                }
        #pragma unroll
        for (int m = 0; m < 4; ++m) {
            af[m][0] = *(const short8*)&LDS[bufA + aRd + (m + 4) * 1024 + c0];
            af[m][1] = *(const short8*)&LDS[bufA + aRd + (m + 4) * 1024 + c1];
        }
        #pragma unroll
        for (int kk = 0; kk < 2; ++kk)
            #pragma unroll
            for (int m = 0; m < 4; ++m)
                #pragma unroll
                for (int n = 0; n < 2; ++n) {
                    acc[m + 4][n]     = MFMA_B16(af[m][kk], bl[n][kk], acc[m + 4][n], 0, 0, 0);
                    acc[m + 4][n + 2] = MFMA_B16(af[m][kk], bh[n][kk], acc[m + 4][n + 2], 0, 0, 0);
                }
    }
    #pragma unroll
    for (int m = 0; m < 8; ++m)
        #pragma unroll
        for (int n = 0; n < 4; ++n)
            #pragma unroll
            for (int j = 0; j < 4; ++j) {
                int row = brow + wr * 128 + m * 16 + l4 * 4 + j;
                int col = bcol + wc * 64 + n * 16 + l15;
                Cs[(size_t)row * ldc + col] = f2bf(acc[m][n][j]);
            }
}

// ---------------- split-K reduce ----------------
__global__ void addparts(const unsigned short* __restrict__ p0,
                         const unsigned short* __restrict__ p1,
                         float* __restrict__ out) {
    int i = blockIdx.x * 256 + threadIdx.x;
    short8 a = ((const short8*)p0)[i];
    short8 b = ((const short8*)p1)[i];
    f4 lo, hi;
    #pragma unroll
    for (int j = 0; j < 4; ++j)
        lo[j] = bf2f((unsigned short)a[j]) + bf2f((unsigned short)b[j]);
    #pragma unroll
    for (int j = 0; j < 4; ++j)
        hi[j] = bf2f((unsigned short)a[j + 4]) + bf2f((unsigned short)b[j + 4]);
    ((f4*)out)[2 * i] = lo;
    ((f4*)out)[2 * i + 1] = hi;
}

// ---------------- merged RoPE + V transpose (one launch) ----------------
__global__ void rope_vt(const unsigned short* __restrict__ qkv,
                        const int* __restrict__ segpos,
                        unsigned short* __restrict__ q_r,
                        unsigned short* __restrict__ k_r,
                        unsigned short* __restrict__ v_t) {
    __shared__ unsigned short tile[64][72];
    const int bx = blockIdx.x, tid = threadIdx.x;
    if (bx < 49152) {
        const int bt = bx & 4095;
        const int hd = (bx >> 12) * 2 + (tid >> 7);
        const int b = bt >> 11, t = bt & 2047;
        const int h = tid & 127;
        const unsigned short* in = (hd < 16)
            ? qkv + (size_t)bt * 4096 + hd * 128
            : qkv + (size_t)bt * 4096 + 2048 + (hd - 16) * 128;
        int pos = segpos[bt];
        int i = h & 63;
        float inv_ts = __expf((float)i * (-9.210340371976184f / 64.f));
        float ang = (float)pos * inv_ts;
        float s = __sinf(ang), c = __cosf(ang);
        float x1 = bf2f(in[i]);
        float x2 = bf2f(in[i + 64]);
        float o = (h < 64) ? (x1 * c - x2 * s) : (x2 * c + x1 * s);
        if (hd < 16) {
            q_r[((size_t)((b * 16 + hd) * 2048 + t)) * 128 + h] = f2bf(o);
        } else {
            int kh = hd - 16;
            k_r[((size_t)((b * 8 + kh) * 2048 + t)) * 128 + h] = f2bf(o);
        }
        return;
    }
    {
        const int flat = bx - 49152;
        const int tt0 = (flat & 31) * 64;
        const int y = (flat >> 5) & 15;
        const int b = flat >> 9;
        const int kh = y >> 1, hb = (y & 1) * 64;
        int c = tid & 63, rq = tid >> 6;
        #pragma unroll
        for (int r = 0; r < 16; ++r) {
            int tt = r * 4 + rq;
            tile[tt][c] = qkv[(size_t)(b * 2048 + tt0 + tt) * 4096 + 3072 + kh * 128 + hb + c];
        }
        __syncthreads();
        #pragma unroll
        for (int r = 0; r < 16; ++r) {
            int hr = r * 4 + rq;
            v_t[((size_t)(b * 8 + kh) * 128 + hb + hr) * 2048 + tt0 + c] = tile[c][hr];
        }
    }
}

// ---------------- flash attention, QBLK=64 (r12 optimum; fixed-max softmax; ones-MFMA l) ----------------

__device__ __forceinline__ void stage_kv(const unsigned short* kbase, const unsigned short* vbase,
                                         unsigned short* Ksb, unsigned short* Vtb,
                                         int st, int tid) {
    #pragma unroll
    for (int r = 0; r < 2; ++r) {
        int e = (r * 512 + tid) * 8;
        int krow = e >> 7, kcol = e & 127;
        gload_lds16(kbase + (size_t)(st * 64 + krow) * 128 + (kcol ^ ((krow & 7) << 3)), Ksb + e);
        int vrow = e >> 6, vcol = e & 63;
        gload_lds16(vbase + (size_t)vrow * 2048 + st * 64 + (vcol ^ ((vrow & 7) << 3)), Vtb + e);
    }
}

__global__ __launch_bounds__(512, 4)
void attn_kernel(const unsigned short* __restrict__ q_r,
                 const unsigned short* __restrict__ k_r,
                 const unsigned short* __restrict__ v_t,
                 unsigned short* __restrict__ enc) {
    __shared__ __align__(16) unsigned short Ks[2][64 * 128];
    __shared__ __align__(16) unsigned short Vt[2][128 * 64];
    __shared__ __align__(16) unsigned short Pl[8][16 * 64];
    const int tid = threadIdx.x, lane = tid & 63, wave = tid >> 6;
    const int l15 = lane & 15, l4 = lane >> 4;
    const int flat = blockIdx.x;
    const int xcd = flat & 7, g = flat >> 3;
    const int pair = xcd * 2 + (g >> 5);
    const int qb = (g & 32) ? (g & 31) : 31 - (g & 31);   // complementary CU pairing
    const int kh = pair >> 1, b = pair & 1;
    const int n = kh * 2 + (wave >> 2);
    const int wq = wave & 3;
    short8 qf[4];
    {
        const unsigned short* qp =
            q_r + ((size_t)((b * 16 + n) * 2048 + qb * 64 + wq * 16 + l15)) * 128 + l4 * 8;
        #pragma unroll
        for (int kk = 0; kk < 4; ++kk) qf[kk] = *(const short8*)(qp + kk * 32);
    }
    short8 ones;
    #pragma unroll
    for (int e = 0; e < 8; ++e) ones[e] = (short)0x3F80;   // bf16 1.0
    f32x4 Of[8] = {};
    f32x4 accl = {};
    int t_lo = qb * 64 - 1023; if (t_lo < 0) t_lo = 0;
    const int st0 = t_lo >> 6;
    const unsigned short* kbase = k_r + (size_t)(b * 8 + kh) * 2048 * 128;
    const unsigned short* vbase = v_t + (size_t)(b * 8 + kh) * 128 * 2048;

    stage_kv(kbase, vbase, Ks[0], Vt[0], st0, tid);
    __syncthreads();
    int cur = 0;
    for (int st = st0; st <= qb; ++st) {
        if (st < qb)
            stage_kv(kbase, vbase, Ks[cur ^ 1], Vt[cur ^ 1], st + 1, tid);
        // ---- QK^T ----
        f32x4 sf[4] = {};
        __builtin_amdgcn_s_setprio(1);
        #pragma unroll
        for (int nc = 0; nc < 4; ++nc) {
            int row = nc * 16 + l15;
            int sw = (l15 & 7) << 3;
            #pragma unroll
            for (int kk = 0; kk < 4; ++kk) {
                short8 bfr = *(const short8*)&Ks[cur][row * 128 + ((kk * 32 + l4 * 8) ^ sw)];
                sf[nc] = MFMA_B16(qf[kk], bfr, sf[nc], 0, 0, 0);
            }
        }
        __builtin_amdgcn_s_setprio(0);
        // ---- softcap+softmax: sf pre-scaled by log2e/25; p = 2^(-144.27/(2^sf+1)) ----
        const int mode = (st == qb) ? 1 : ((qb >= 16 && st == st0) ? 2 : 0);
        #pragma unroll
        for (int j = 0; j < 4; ++j) {
            int trow = qb * 64 + wq * 16 + l4 * 4 + j;
            int prow = l4 * 4 + j;
            int psw = (prow & 7) << 3;
            float pp[4];
            #pragma unroll
            for (int nc = 0; nc < 4; ++nc) {
                float ex = fexp2(sf[nc][j]);
                float p = fexp2(-144.26950408889634f * __builtin_amdgcn_rcpf(ex + 1.f));
                if (mode) {
                    int s = st * 64 + nc * 16 + l15;
                    bool ok = (mode == 1) ? (s <= trow) : (s >= trow - 1023);
                    p = ok ? p : 0.f;
                }
                pp[nc] = p;
            }
            unsigned int k01 = cvt_pk_bf16(pp[0], pp[1]);
            unsigned int k23 = cvt_pk_bf16(pp[2], pp[3]);
            unsigned short* Pr = &Pl[wave][prow * 64];
            Pr[l15 ^ psw]        = (unsigned short)k01;
            Pr[(16 + l15) ^ psw] = (unsigned short)(k01 >> 16);
            Pr[(32 + l15) ^ psw] = (unsigned short)k23;
            Pr[(48 + l15) ^ psw] = (unsigned short)(k23 >> 16);
        }
        // ---- PV + row-sum (ones-MFMA on the matrix pipe) ----
        {
            int asw = (l15 & 7) << 3;
            __builtin_amdgcn_s_setprio(1);
            #pragma unroll
            for (int ks = 0; ks < 2; ++ks) {
                short8 af = *(const short8*)&Pl[wave][l15 * 64 + ((ks * 32 + l4 * 8) ^ asw)];
                accl = MFMA_B16(af, ones, accl, 0, 0, 0);
                #pragma unroll
                for (int hc = 0; hc < 8; ++hc) {
                    int vrow = hc * 16 + l15;
                    short8 bfr = *(const short8*)&Vt[cur][vrow * 64 + ((ks * 32 + l4 * 8) ^ asw)];
                    Of[hc] = MFMA_B16(af, bfr, Of[hc], 0, 0, 0);
                }
            }
            __builtin_amdgcn_s_setprio(0);
        }
        __syncthreads();
        cur ^= 1;
    }
    f32x4 inv;
    #pragma unroll
    for (int j = 0; j < 4; ++j) inv[j] = 1.f / accl[j];
    #pragma unroll
    for (int hc = 0; hc < 8; ++hc)
        #pragma unroll
        for (int j = 0; j < 4; ++j) {
            size_t row = (size_t)(b * 2048 + qb * 64 + wq * 16 + l4 * 4 + j);
            enc[row * 2048 + n * 128 + hc * 16 + l15] = f2bf(Of[hc][j] * inv[j]);
        }
}

// ---------------- launch ----------------

extern "C" void kernel_launch(void* const* d_in, const int* in_sizes, int n_in,
                              void* d_out, int out_size, void* d_ws, size_t ws_size,
                              hipStream_t stream) {
    const float* x   = (const float*)d_in[0];
    const int* segp  = (const int*)d_in[1];
    const float* wq  = (const float*)d_in[3];
    const float* wkv = (const float*)d_in[4];
    const float* wo  = (const float*)d_in[5];
    float* out = (float*)d_out;
    char* ws = (char*)d_ws;
    if (ws_size < ((size_t)104 << 20)) return;

    unsigned short* xb    = (unsigned short*)(ws);                       // [0,16) MiB
    unsigned short* wqkvt = (unsigned short*)(ws + ((size_t)16 << 20));  // [16,32)
    unsigned short* qkv   = (unsigned short*)(ws + ((size_t)32 << 20));  // [32,64)
    unsigned short* q_r   = (unsigned short*)(ws + ((size_t)64 << 20));  // [64,80)
    unsigned short* k_r   = (unsigned short*)(ws + ((size_t)80 << 20));  // [80,88)
    unsigned short* v_t   = (unsigned short*)(ws + ((size_t)88 << 20));  // [88,96)
    unsigned short* wo_t  = (unsigned short*)(ws + ((size_t)96 << 20));  // [96,104)
    unsigned short* enc   = (unsigned short*)(ws + ((size_t)32 << 20));  // reuse qkv
    unsigned short* part  = (unsigned short*)(ws + ((size_t)64 << 20));  // reuse q_r/k_r/v_t

    conv_all<<<11264, 256, 0, stream>>>(x, xb, wq, wkv, wqkvt, wo, wo_t);
    gemm8p<<<dim3(16, 16), 512, 0, stream>>>(xb, wqkvt, qkv, 2048, 4096, 32, 0, 0);
    rope_vt<<<50176, 256, 0, stream>>>(qkv, segp, q_r, k_r, v_t);
    attn_kernel<<<512, 512, 0, stream>>>(q_r, k_r, v_t, enc);
    gemm8p<<<dim3(8, 32), 512, 0, stream>>>(enc, wo_t, part, 2048, 2048, 16, 1, (size_t)4096 * 2048);
    addparts<<<4096, 256, 0, stream>>>(part, part + (size_t)4096 * 2048, out);
}